// Round 2
// baseline (402.844 us; speedup 1.0000x reference)
//
#include <hip/hip_runtime.h>
#include <hip/hip_fp16.h>
#include <hip/hip_cooperative_groups.h>

namespace cg = cooperative_groups;

// Problem constants (from reference): B=1024, D_IN=64, D_HID=128.
#define BB      1024
#define DIN     64
#define DHID    128
#define NPAIRS  (1024.0f * 1024.0f)
#define BN_EPS  1e-5f

// Native packed-fp16 vector type: clang emits v_pk_{add,mul,fma,max}_f16
// for operators / __builtin_elementwise_max on this type.
typedef _Float16 h2 __attribute__((ext_vector_type(2)));

struct __align__(16) H24 { h2 h[4]; };

__device__ __forceinline__ h2 mk_h2(float a, float b) {
    h2 r; r.x = (_Float16)a; r.y = (_Float16)b; return r;
}

// dot2 with fp32 accumulator: a.x*b.x + a.y*b.y + acc (v_dot2_f32_f16).
__device__ __forceinline__ float fdot2acc(h2 a, h2 b, float acc) {
#if __has_builtin(__builtin_amdgcn_fdot2)
    return __builtin_amdgcn_fdot2(a, b, acc, false);
#else
    return acc + (float)a.x * (float)b.x + (float)a.y * (float)b.y;
#endif
}

// ---------------------------------------------------------------------------
// Fused pipeline (round-7): one cooperative kernel, 512 blocks x 256 thr,
// grid.sync() between phases. Phase math copied verbatim from the round-0
// kernels (identical per-chain accumulation order -> identical absmax).
//   Phase A (blocks 0-255): U/V projection (ex-K1, 4 x-rows/block).
//   Phase B (all 512):      per-channel sum/sumsq of relu(u+v) (ex-K2,
//                           8 i x 128 jpairs per block).
//   Phase C (blocks 0-15):  reduce partial[512][256] -> sums (ex-K2b).
//   Phase D (all 512):      output (ex-K3, 8 i x 256 j per block).
// Rationale: round-0/1 showed dur_us is insensitive to grid/occupancy;
// remaining controllable costs are the 3 inter-kernel drain/refill gaps +
// K2b launch + L2 reuse across phases. Fusion removes all of them and makes
// the single kernel's duration directly visible in the profile.
// ---------------------------------------------------------------------------
__global__ __launch_bounds__(256, 2) void fused_all(
    const float* __restrict__ x, const float* __restrict__ W1,
    const float* __restrict__ b1,
    const float* __restrict__ gamma, const float* __restrict__ beta,
    const float* __restrict__ W2, const float* __restrict__ b2,
    float* __restrict__ out,
    h2* __restrict__ Uph, h2* __restrict__ Vp2, h2* __restrict__ Vp3,
    float* __restrict__ partial, float* __restrict__ sums)
{
    cg::grid_group grid = cg::this_grid();
    const int tid = threadIdx.x;
    const int bid = blockIdx.x;          // 0..511

    // ---- LDS (phases use disjoint arrays; total ~12.9 KB, 2 blocks/CU ok)
    __shared__ float xs[4][DIN];                 // phase A
    __shared__ float ls[8][DHID], lq[8][DHID];   // phase B (8 KB)
    __shared__ float lred[16][17];               // phase C
    __shared__ h2    lutp[DHID][8];              // phase D
    __shared__ h2    lsch[DHID];
    __shared__ float ltp[DHID];
    __shared__ float lt;

    // ======================= Phase A: projection =======================
    if (bid < 256) {
        const int c     = tid & 127;
        const int hf    = tid >> 7;          // 0..1
        const int rbase = bid * 4;

        xs[tid >> 6][tid & 63] = x[rbase * DIN + tid];
        __syncthreads();

        float u0 = 0.f, u1 = 0.f, v0 = 0.f, v1 = 0.f;
        const int r0 = hf * 2;
        #pragma unroll 8
        for (int k = 0; k < DIN; ++k) {
            const float wt = W1[k * DHID + c];          // coalesced over c
            const float wb = W1[(DIN + k) * DHID + c];
            const float x0 = xs[r0][k];                  // LDS broadcast
            const float x1 = xs[r0 + 1][k];
            u0 = fmaf(x0, wt, u0); v0 = fmaf(x0, wb, v0);
            u1 = fmaf(x1, wt, u1); v1 = fmaf(x1, wb, v1);
        }
        const float bbv = b1[c];
        const int row0 = rbase + r0;                     // even
        Uph[row0 * DHID + c]       = mk_h2(u0 + bbv, u0 + bbv);
        Uph[(row0 + 1) * DHID + c] = mk_h2(u1 + bbv, u1 + bbv);
        const h2 vp = mk_h2(v0, v1);
        const int jp = row0 >> 1;
        Vp2[jp * DHID + c]      = vp;
        Vp3[c * (BB / 2) + jp]  = vp;
    }
    __threadfence();
    grid.sync();

    // ======================= Phase B: stats =======================
    {
        const int c0  = (tid & 31) * 4;          // channel group
        const int jl  = tid >> 5;                // 0..7
        const int bx  = bid & 127;
        const int by  = bid >> 7;                // 0..3
        const int ib  = bx * 8;                  // 8 i's
        const int jpb = by * 128;                // 128 jpairs

        H24 u[8];
        #pragma unroll
        for (int ii = 0; ii < 8; ++ii)
            u[ii] = *(const H24*)&Uph[(ib + ii) * DHID + c0];   // 16B aligned

        float s0=0.f,s1=0.f,s2=0.f,s3=0.f, q0=0.f,q1=0.f,q2=0.f,q3=0.f;
        const h2 zero2 = mk_h2(0.f, 0.f);
        const h2 one2  = mk_h2(1.f, 1.f);
        const h2* vp = Vp2 + (jpb + jl) * DHID + c0;
        #pragma unroll 4
        for (int t = 0; t < 16; ++t) {
            const H24 v = *(const H24*)&vp[t * 8 * DHID];
            #pragma unroll
            for (int ii = 0; ii < 8; ++ii) {
                h2 r;
                r = __builtin_elementwise_max(u[ii].h[0] + v.h[0], zero2);
                s0 = fdot2acc(r, one2, s0); q0 = fdot2acc(r, r, q0);
                r = __builtin_elementwise_max(u[ii].h[1] + v.h[1], zero2);
                s1 = fdot2acc(r, one2, s1); q1 = fdot2acc(r, r, q1);
                r = __builtin_elementwise_max(u[ii].h[2] + v.h[2], zero2);
                s2 = fdot2acc(r, one2, s2); q2 = fdot2acc(r, r, q2);
                r = __builtin_elementwise_max(u[ii].h[3] + v.h[3], zero2);
                s3 = fdot2acc(r, one2, s3); q3 = fdot2acc(r, r, q3);
            }
        }

        {
            float4 fs = {s0, s1, s2, s3};
            float4 fq = {q0, q1, q2, q3};
            *(float4*)&ls[jl][c0] = fs;
            *(float4*)&lq[jl][c0] = fq;
        }
        __syncthreads();

        if (tid < 32) {
            float4 S = *(float4*)&ls[0][c0];
            float4 Q = *(float4*)&lq[0][c0];
            #pragma unroll
            for (int g = 1; g < 8; ++g) {
                S.x += ls[g][c0 + 0]; S.y += ls[g][c0 + 1];
                S.z += ls[g][c0 + 2]; S.w += ls[g][c0 + 3];
                Q.x += lq[g][c0 + 0]; Q.y += lq[g][c0 + 1];
                Q.z += lq[g][c0 + 2]; Q.w += lq[g][c0 + 3];
            }
            const int pbid = by * 128 + bx;             // 0..511
            *(float4*)&partial[pbid * 256 + c0]        = S;
            *(float4*)&partial[pbid * 256 + DHID + c0] = Q;
        }
    }
    __threadfence();
    grid.sync();

    // ======================= Phase C: reduce partial -> sums ===========
    if (bid < 16) {
        const int cl  = tid & 15;           // column-in-block
        const int rg  = tid >> 4;           // 0..15 row group
        const int col = bid * 16 + cl;

        float acc = 0.f;
        #pragma unroll 8
        for (int t = 0; t < 32; ++t)
            acc += partial[(rg + 16 * t) * 256 + col];
        lred[rg][cl] = acc;
        __syncthreads();
        if (tid < 16) {
            float a = 0.f;
            #pragma unroll
            for (int g = 0; g < 16; ++g) a += lred[g][tid];
            sums[bid * 16 + tid] = a;
        }
    }
    __threadfence();
    grid.sync();

    // ======================= Phase D: output =======================
    {
        const int bx    = bid & 127;
        const int by    = bid >> 7;             // 0..3
        const int ib    = bx * 8;
        const int jbase = by * 256;

        if (tid < DHID) {
            const float invN = 1.0f / NPAIRS;
            const float mean = sums[tid] * invN;
            const float var  = fmaxf(sums[DHID + tid] * invN - mean * mean, 0.f);
            const float inv  = rsqrtf(var + BN_EPS);
            const float gi   = gamma[tid] * inv;
            const float w2   = W2[tid];
            lsch[tid] = mk_h2(gi * w2, gi * w2);
            ltp[tid]  = (beta[tid] - mean * gi) * w2;
        }
        // stage 8 rows of packed U into LDS, transposed to [c][i]
        #pragma unroll
        for (int t = tid; t < 8 * DHID; t += 256)
            lutp[t & 127][t >> 7] = Uph[(ib + (t >> 7)) * DHID + (t & 127)];
        __syncthreads();
        // wave-0 shuffle reduction of ltp -> lt
        if (tid < 64) {
            float tl = ltp[tid] + ltp[tid + 64];
            #pragma unroll
            for (int off = 32; off >= 1; off >>= 1)
                tl += __shfl_down(tl, off, 64);
            if (tid == 0) lt = tl + b2[0];
        }
        __syncthreads();
        const float tconst = lt;

        const int i0   = (tid >> 6) * 2;              // 0,2,4,6 (wave-uniform)
        const int lane = tid & 63;
        const int jp0  = (jbase >> 1) + lane * 2;     // 2 adjacent jpairs = 4 j

        const h2 zero2 = mk_h2(0.f, 0.f);
        h2 a00 = zero2, a01 = zero2, a10 = zero2, a11 = zero2;
        float2 f00 = {0.f,0.f}, f01 = {0.f,0.f}, f10 = {0.f,0.f}, f11 = {0.f,0.f};

        for (int cb = 0; cb < 4; ++cb) {
            #pragma unroll 8
            for (int ci = 0; ci < 32; ++ci) {
                const int c = cb * 32 + ci;
                const h2 v0  = Vp3[c * (BB / 2) + jp0];      // merged 8B
                const h2 v1  = Vp3[c * (BB / 2) + jp0 + 1];
                const h2 sc  = lsch[c];                      // LDS broadcast
                const h2 uu0 = lutp[c][i0];                  // merged 8B
                const h2 uu1 = lutp[c][i0 + 1];
                a00 = __builtin_elementwise_max(uu0 + v0, zero2) * sc + a00;
                a01 = __builtin_elementwise_max(uu0 + v1, zero2) * sc + a01;
                a10 = __builtin_elementwise_max(uu1 + v0, zero2) * sc + a10;
                a11 = __builtin_elementwise_max(uu1 + v1, zero2) * sc + a11;
            }
            f00.x += (float)a00.x; f00.y += (float)a00.y; a00 = zero2;
            f01.x += (float)a01.x; f01.y += (float)a01.y; a01 = zero2;
            f10.x += (float)a10.x; f10.y += (float)a10.y; a10 = zero2;
            f11.x += (float)a11.x; f11.y += (float)a11.y; a11 = zero2;
        }

        const int j0 = jbase + lane * 4;
        float4 o;
        o.x = f00.x + tconst; o.y = f00.y + tconst;
        o.z = f01.x + tconst; o.w = f01.y + tconst;
        *(float4*)&out[(ib + i0) * BB + j0] = o;
        o.x = f10.x + tconst; o.y = f10.y + tconst;
        o.z = f11.x + tconst; o.w = f11.y + tconst;
        *(float4*)&out[(ib + i0 + 1) * BB + j0] = o;
    }
}

extern "C" void kernel_launch(void* const* d_in, const int* in_sizes, int n_in,
                              void* d_out, int out_size, void* d_ws, size_t ws_size,
                              hipStream_t stream) {
    const float* x     = (const float*)d_in[0];  // (1024, 64)
    const float* W1    = (const float*)d_in[1];  // (128, 128)
    const float* b1    = (const float*)d_in[2];  // (128,)
    const float* gamma = (const float*)d_in[3];  // (128,)
    const float* beta  = (const float*)d_in[4];  // (128,)
    const float* W2    = (const float*)d_in[5];  // (128,)
    const float* b2    = (const float*)d_in[6];  // (1,)
    float* out = (float*)d_out;                  // (1024*1024,)

    float* ws = (float*)d_ws;
    h2* Uph        = (h2*)ws;                    // 1024*128 h2 (512 KB)
    h2* Vp2        = (h2*)(ws + 131072);         // 512*128 h2 (256 KB)
    h2* Vp3        = (h2*)(ws + 196608);         // 128*512 h2 (256 KB)
    float* partial = ws + 262144;                // 512*256 fp32 (512 KB)
    float* sums    = ws + 524288;                // 256 (sum | sumsq)

    void* args[] = {
        (void*)&x, (void*)&W1, (void*)&b1, (void*)&gamma, (void*)&beta,
        (void*)&W2, (void*)&b2, (void*)&out, (void*)&Uph, (void*)&Vp2,
        (void*)&Vp3, (void*)&partial, (void*)&sums
    };
    hipLaunchCooperativeKernel((const void*)fused_all, dim3(512), dim3(256),
                               args, 0, stream);
}

// Round 3
// 118.629 us; speedup vs baseline: 3.3958x; 3.3958x over previous
//
#include <hip/hip_runtime.h>
#include <hip/hip_fp16.h>

// Problem constants (from reference): B=1024, D_IN=64, D_HID=128.
#define BB      1024
#define DIN     64
#define DHID    128
#define NPAIRS  (1024.0f * 1024.0f)
#define BN_EPS  1e-5f

// Native packed-fp16 vector type: clang emits v_pk_{add,mul,fma,max}_f16
// for operators / __builtin_elementwise_max on this type.
typedef _Float16 h2 __attribute__((ext_vector_type(2)));

struct __align__(16) H24 { h2 h[4]; };

__device__ __forceinline__ h2 mk_h2(float a, float b) {
    h2 r; r.x = (_Float16)a; r.y = (_Float16)b; return r;
}

// dot2 with fp32 accumulator: a.x*b.x + a.y*b.y + acc (v_dot2_f32_f16).
__device__ __forceinline__ float fdot2acc(h2 a, h2 b, float acc) {
#if __has_builtin(__builtin_amdgcn_fdot2)
    return __builtin_amdgcn_fdot2(a, b, acc, false);
#else
    return acc + (float)a.x * (float)b.x + (float)a.y * (float)b.y;
#endif
}

// ---------------------------------------------------------------------------
// Round-8 structure: back to multi-kernel (round-2's cooperative fusion cost
// 330us -- grid.sync spins ~100us each on this part; never again). Three
// kernels now: K1 proj -> K2 stats (with folded last-block reduction, no
// separate K2b launch) -> K3 out. The ~73us/iter of harness overhead
// (poison fills etc., measured round-2: 402.8 total - 330.2 kernel) is
// fixed; this round trims the controllable ~26us slice by removing one
// launch + gap from the dependency chain.
// ---------------------------------------------------------------------------

// K1: U[i][c] = x[i,:] . W1[0:64, c] + b1[c];  V[j][c] = x[j,:] . W1[64:, c]
// Also zeroes K2's done-counter (workspace is poisoned every iteration).
__global__ __launch_bounds__(256) void k1_proj(
    const float* __restrict__ x, const float* __restrict__ W1,
    const float* __restrict__ b1,
    h2* __restrict__ Uph, h2* __restrict__ Vp2, h2* __restrict__ Vp3,
    unsigned int* __restrict__ counter)
{
    if (blockIdx.x == 0 && threadIdx.x == 0) counter[0] = 0u;

    __shared__ float xs[4][DIN];
    const int c     = threadIdx.x & 127;
    const int hf    = threadIdx.x >> 7;      // 0..1
    const int rbase = blockIdx.x * 4;

    xs[threadIdx.x >> 6][threadIdx.x & 63] = x[rbase * DIN + threadIdx.x];
    __syncthreads();

    float u0 = 0.f, u1 = 0.f, v0 = 0.f, v1 = 0.f;
    const int r0 = hf * 2;
    #pragma unroll 8
    for (int k = 0; k < DIN; ++k) {
        const float wt = W1[k * DHID + c];          // coalesced over c
        const float wb = W1[(DIN + k) * DHID + c];
        const float x0 = xs[r0][k];                  // LDS broadcast
        const float x1 = xs[r0 + 1][k];
        u0 = fmaf(x0, wt, u0); v0 = fmaf(x0, wb, v0);
        u1 = fmaf(x1, wt, u1); v1 = fmaf(x1, wb, v1);
    }
    const float bbv = b1[c];
    const int row0 = rbase + r0;                     // even
    Uph[row0 * DHID + c]       = mk_h2(u0 + bbv, u0 + bbv);
    Uph[(row0 + 1) * DHID + c] = mk_h2(u1 + bbv, u1 + bbv);
    const h2 vp = mk_h2(v0, v1);
    const int jp = row0 >> 1;
    Vp2[jp * DHID + c]      = vp;
    Vp3[c * (BB / 2) + jp]  = vp;   // small scattered store, 256 KB total
}

// K2: per-channel sum / sumsq of relu(U[i,c] + V[j,c]), packed fp16.
// Grid: dim3(128, 2) = 256 blocks. Block = 8 i x 256 jpairs (512 j).
// Thread: 4 channels x 8 u-rows in registers, jpair-stride-8 lane.
// Inner: pk_add + pk_max + 2x v_dot2_f32_f16 = 4 instr / 2 elements
// (fp32 accumulators -> stats precision preserved).
// Tail: per-block partial stores, then LAST-BLOCK-DONE reduction folds the
// old K2b kernel in (saves one launch + inter-kernel gap). No spinning:
// only the last-arriving block does the 256x256 column-coalesced reduce.
__global__ __launch_bounds__(256) void k2_stats(
    const h2* __restrict__ Uph, const h2* __restrict__ Vp2,
    float* __restrict__ partial, float* __restrict__ sums,
    unsigned int* __restrict__ counter)
{
    const int c0  = (threadIdx.x & 31) * 4;   // channel group
    const int jl  = threadIdx.x >> 5;         // 0..7
    const int ib  = blockIdx.x * 8;           // 8 i's  (gridDim.x = 128)
    const int jpb = blockIdx.y * 256;         // 256 jpairs (gridDim.y = 2)

    H24 u[8];
    #pragma unroll
    for (int ii = 0; ii < 8; ++ii)
        u[ii] = *(const H24*)&Uph[(ib + ii) * DHID + c0];   // 16B aligned

    float s0=0.f,s1=0.f,s2=0.f,s3=0.f, q0=0.f,q1=0.f,q2=0.f,q3=0.f;
    const h2 zero2 = mk_h2(0.f, 0.f);
    const h2 one2  = mk_h2(1.f, 1.f);
    const h2* vp = Vp2 + (jpb + jl) * DHID + c0;
    #pragma unroll 4
    for (int t = 0; t < 32; ++t) {
        const H24 v = *(const H24*)&vp[t * 8 * DHID];
        #pragma unroll
        for (int ii = 0; ii < 8; ++ii) {
            h2 r;
            r = __builtin_elementwise_max(u[ii].h[0] + v.h[0], zero2);
            s0 = fdot2acc(r, one2, s0); q0 = fdot2acc(r, r, q0);
            r = __builtin_elementwise_max(u[ii].h[1] + v.h[1], zero2);
            s1 = fdot2acc(r, one2, s1); q1 = fdot2acc(r, r, q1);
            r = __builtin_elementwise_max(u[ii].h[2] + v.h[2], zero2);
            s2 = fdot2acc(r, one2, s2); q2 = fdot2acc(r, r, q2);
            r = __builtin_elementwise_max(u[ii].h[3] + v.h[3], zero2);
            s3 = fdot2acc(r, one2, s3); q3 = fdot2acc(r, r, q3);
        }
    }

    __shared__ float ls[8][DHID];
    __shared__ float lq[8][DHID];
    {
        float4 fs = {s0, s1, s2, s3};
        float4 fq = {q0, q1, q2, q3};
        *(float4*)&ls[jl][c0] = fs;
        *(float4*)&lq[jl][c0] = fq;
    }
    __syncthreads();

    if (threadIdx.x < 32) {
        float4 S = *(float4*)&ls[0][c0];
        float4 Q = *(float4*)&lq[0][c0];
        #pragma unroll
        for (int g = 1; g < 8; ++g) {
            S.x += ls[g][c0 + 0]; S.y += ls[g][c0 + 1];
            S.z += ls[g][c0 + 2]; S.w += ls[g][c0 + 3];
            Q.x += lq[g][c0 + 0]; Q.y += lq[g][c0 + 1];
            Q.z += lq[g][c0 + 2]; Q.w += lq[g][c0 + 3];
        }
        const int pbid = blockIdx.y * 128 + blockIdx.x;   // 0..255
        *(float4*)&partial[pbid * 256 + c0]        = S;
        *(float4*)&partial[pbid * 256 + DHID + c0] = Q;
        __threadfence();   // release: my partial row is device-visible
    }
    __syncthreads();

    __shared__ bool amLast;
    if (threadIdx.x == 0)
        amLast = (atomicAdd(counter, 1u) == 255u);   // device-scope
    __syncthreads();

    if (amLast) {
        __threadfence();   // acquire: see all 256 partial rows
        const int col = threadIdx.x;                 // 0..255, coalesced
        float acc = 0.f;
        #pragma unroll 8
        for (int r = 0; r < 256; ++r)
            acc += partial[r * 256 + col];
        sums[col] = acc;
    }
}

// K3: out[i,j] = t + sum_c relu(U[i,c] + V[j,c]) * s[c], packed fp16.
// Grid: dim3(128, 8) = 1024 blocks. Block = 8 i x 128 j; thread = 2 i x
// 1 jpair (2 j). Inner per (i,jpair): pk_add+pk_max+pk_fma = 3 instr /
// 2 elements. fp16 accumulators flushed to fp32 every 32 c.
__global__ __launch_bounds__(256, 4) void k3_out(
    const h2* __restrict__ Uph, const h2* __restrict__ Vp3,
    const float* __restrict__ sums,
    const float* __restrict__ gamma, const float* __restrict__ beta,
    const float* __restrict__ W2, const float* __restrict__ b2,
    float* __restrict__ out)
{
    __shared__ h2    lutp[DHID][8];  // U packed, transposed: [c][i-local]
    __shared__ h2    lsch[DHID];     // h2(s_c, s_c)
    __shared__ float ltp[DHID];
    __shared__ float lt;

    const int tid   = threadIdx.x;
    const int ib    = blockIdx.x * 8;     // gridDim.x = 128
    const int jbase = blockIdx.y * 128;   // gridDim.y = 8

    if (tid < DHID) {
        const float invN = 1.0f / NPAIRS;
        const float mean = sums[tid] * invN;
        const float var  = fmaxf(sums[DHID + tid] * invN - mean * mean, 0.f);
        const float inv  = rsqrtf(var + BN_EPS);
        const float gi   = gamma[tid] * inv;
        const float w2   = W2[tid];
        lsch[tid] = mk_h2(gi * w2, gi * w2);
        ltp[tid]  = (beta[tid] - mean * gi) * w2;
    }
    // stage 8 rows of packed U into LDS, transposed to [c][i]
    #pragma unroll
    for (int t = tid; t < 8 * DHID; t += 256)
        lutp[t & 127][t >> 7] = Uph[(ib + (t >> 7)) * DHID + (t & 127)];
    __syncthreads();
    // wave-0 shuffle reduction of ltp -> lt
    if (tid < 64) {
        float tl = ltp[tid] + ltp[tid + 64];
        #pragma unroll
        for (int off = 32; off >= 1; off >>= 1)
            tl += __shfl_down(tl, off, 64);
        if (tid == 0) lt = tl + b2[0];
    }
    __syncthreads();
    const float tconst = lt;

    const int i0   = (tid >> 6) * 2;              // 0,2,4,6 (wave-uniform)
    const int lane = tid & 63;
    const int jp0  = (jbase >> 1) + lane;         // 1 jpair = 2 j per lane

    const h2 zero2 = mk_h2(0.f, 0.f);
    h2 a00 = zero2, a10 = zero2;
    float2 f00 = {0.f, 0.f}, f10 = {0.f, 0.f};

    for (int cb = 0; cb < 4; ++cb) {
        #pragma unroll 8
        for (int ci = 0; ci < 32; ++ci) {
            const int c = cb * 32 + ci;
            const h2 v0  = Vp3[c * (BB / 2) + jp0];      // coalesced 4B/lane
            const h2 sc  = lsch[c];                      // LDS broadcast
            const h2 uu0 = lutp[c][i0];                  // merged 8B
            const h2 uu1 = lutp[c][i0 + 1];
            a00 = __builtin_elementwise_max(uu0 + v0, zero2) * sc + a00;
            a10 = __builtin_elementwise_max(uu1 + v0, zero2) * sc + a10;
        }
        f00.x += (float)a00.x; f00.y += (float)a00.y; a00 = zero2;
        f10.x += (float)a10.x; f10.y += (float)a10.y; a10 = zero2;
    }

    const int j0 = jbase + lane * 2;
    float2 o;
    o.x = f00.x + tconst; o.y = f00.y + tconst;
    *(float2*)&out[(ib + i0) * BB + j0] = o;
    o.x = f10.x + tconst; o.y = f10.y + tconst;
    *(float2*)&out[(ib + i0 + 1) * BB + j0] = o;
}

extern "C" void kernel_launch(void* const* d_in, const int* in_sizes, int n_in,
                              void* d_out, int out_size, void* d_ws, size_t ws_size,
                              hipStream_t stream) {
    const float* x     = (const float*)d_in[0];  // (1024, 64)
    const float* W1    = (const float*)d_in[1];  // (128, 128)
    const float* b1    = (const float*)d_in[2];  // (128,)
    const float* gamma = (const float*)d_in[3];  // (128,)
    const float* beta  = (const float*)d_in[4];  // (128,)
    const float* W2    = (const float*)d_in[5];  // (128,)
    const float* b2    = (const float*)d_in[6];  // (1,)
    float* out = (float*)d_out;                  // (1024*1024,)

    float* ws = (float*)d_ws;
    h2* Uph        = (h2*)ws;                    // 1024*128 h2 (512 KB)
    h2* Vp2        = (h2*)(ws + 131072);         // 512*128 h2 (256 KB)
    h2* Vp3        = (h2*)(ws + 196608);         // 128*512 h2 (256 KB)
    float* partial = ws + 262144;                // 256*256 fp32 (256 KB)
    float* sums    = ws + 327680;                // 256 (sum | sumsq)
    unsigned int* counter = (unsigned int*)(ws + 327936);

    k1_proj<<<256, 256, 0, stream>>>(x, W1, b1, Uph, Vp2, Vp3, counter);
    k2_stats<<<dim3(128, 2), 256, 0, stream>>>(Uph, Vp2, partial, sums, counter);
    k3_out<<<dim3(128, 8), 256, 0, stream>>>(Uph, Vp3, sums, gamma, beta, W2, b2, out);
}